// Round 6
// baseline (336.735 us; speedup 1.0000x reference)
//
#include <hip/hip_runtime.h>
#include <hip/hip_bf16.h>
#include <math.h>

#define DIMV 256
#define DV 32
#define QKVS 768   // interleaved row stride: q[256] | k[256] | v[256]

typedef __attribute__((ext_vector_type(8))) short bf16x8;
typedef __attribute__((ext_vector_type(4))) float f32x4;

#define EXPS(x) __expf(x)
#define SCORE_SCALE 0.17677669529663687f

static __device__ __forceinline__ unsigned short f2bf(float f) {
    unsigned x = __float_as_uint(f);
    x += 0x7FFF + ((x >> 16) & 1);   // round-to-nearest-even
    return (unsigned short)(x >> 16);
}
static __device__ __forceinline__ float bf2f(unsigned short u) {
    return __uint_as_float(((unsigned)u) << 16);
}

static __device__ __forceinline__ void async16(const void* g, void* lds) {
    __builtin_amdgcn_global_load_lds(
        (const __attribute__((address_space(1))) void*)g,
        (__attribute__((address_space(3))) void*)lds, 16, 0, 0);
}

// ---------------- weight f32 -> bf16 + fused degree count ----------------

__global__ void cvt_w_count(const float* __restrict__ Wq, const float* __restrict__ Wk,
                            const float* __restrict__ Wv, const float* __restrict__ Wo,
                            unsigned short* __restrict__ Wcat,
                            const int* __restrict__ dst, int* __restrict__ deg, int E) {
    const float* W = blockIdx.y == 0 ? Wq : blockIdx.y == 1 ? Wk : blockIdx.y == 2 ? Wv : Wo;
    int i = blockIdx.x * 256 + threadIdx.x;          // float4 index, 16384 per matrix
    float4 v = ((const float4*)W)[i];
    ushort4 o;
    o.x = f2bf(v.x); o.y = f2bf(v.y); o.z = f2bf(v.z); o.w = f2bf(v.w);
    ((ushort4*)(Wcat + (size_t)blockIdx.y * 65536))[i] = o;

    // fused degree count (grid-stride over E)
    int gid = (blockIdx.y * gridDim.x + blockIdx.x) * 256 + threadIdx.x;
    int nthr = gridDim.x * gridDim.y * 256;
    for (int e = gid; e < E; e += nthr) atomicAdd(&deg[dst[e]], 1);
}

// ---------------- CSR build (R3 config — measured fast) ----------------

__global__ void zero_i32(int* __restrict__ p, int n) {
    int i = blockIdx.x * blockDim.x + threadIdx.x;
    if (i < n) p[i] = 0;
}

__global__ void block_sum(const int* __restrict__ deg, int* __restrict__ bsum, int n) {
    __shared__ int sm[256];
    int i = blockIdx.x * 256 + threadIdx.x;
    sm[threadIdx.x] = (i < n) ? deg[i] : 0;
    __syncthreads();
    for (int s = 128; s > 0; s >>= 1) {
        if (threadIdx.x < s) sm[threadIdx.x] += sm[threadIdx.x + s];
        __syncthreads();
    }
    if (threadIdx.x == 0) bsum[blockIdx.x] = sm[0];
}

__global__ void scan_bsum(int* __restrict__ bsum, int nb) {
    if (threadIdx.x == 0) {
        int r = 0;
        for (int i = 0; i < nb; ++i) { int v = bsum[i]; bsum[i] = r; r += v; }
    }
}

__global__ void scan_final(const int* __restrict__ deg, const int* __restrict__ bsum,
                           int* __restrict__ offsets, int* __restrict__ cursor, int n) {
    __shared__ int sm[256];
    int i = blockIdx.x * 256 + threadIdx.x;
    int v = (i < n) ? deg[i] : 0;
    sm[threadIdx.x] = v;
    __syncthreads();
    for (int s = 1; s < 256; s <<= 1) {
        int t = (threadIdx.x >= s) ? sm[threadIdx.x - s] : 0;
        __syncthreads();
        sm[threadIdx.x] += t;
        __syncthreads();
    }
    int excl = sm[threadIdx.x] - v + bsum[blockIdx.x];
    if (i < n) { offsets[i] = excl; cursor[i] = excl; }
    if (i == n - 1) offsets[n] = excl + v;
}

// ---------------- fused MFMA GEMM: C[mat] = A @ W[mat]^T + b[mat] ----------------
// A [M,256] (f32 or bf16) row-major; Wcat [nmat][256][256] bf16 row-major.
// A-strip in registers (read once); W tiles (32 cols x 256 K = 16 KB) double-
// buffered in LDS via global_load_lds (pre-swizzled source + swizzled ds_read).
// K-loop uses raw s_barrier + counted vmcnt(4): next-tile DMA stays in flight
// across barriers (no per-tile full drain).
// Optional fused edge-scatter prologue (hidden under A-load + tile-0 staging).

template<bool AF32, bool OF32, int OSTRIDE, int MATSTRIDE, bool SCATTER>
__global__ __launch_bounds__(256, 4)
void gemm_fused(const void* __restrict__ Ain,
                const unsigned short* __restrict__ Wcat,
                const float* __restrict__ b0, const float* __restrict__ b1,
                const float* __restrict__ b2,
                void* __restrict__ Cout, int M, int ntiles,
                const int* __restrict__ esrc, const int* __restrict__ edst,
                int* __restrict__ cursor, int* __restrict__ perm_src, int E) {
    __shared__ unsigned short Bls[2][32 * 256];   // 2 x 16 KB
    const int tid = threadIdx.x;
    const int w = tid >> 6, lane = tid & 63;
    const int rg = w >> 1, cg = w & 1;
    const int lrow = lane & 15, lkg = lane >> 4;
    const int row0 = blockIdx.x * 64;

    // stage tile 0 (pre-swizzled source, linear LDS dest)
    {
        const char* gb = (const char*)Wcat;
        #pragma unroll
        for (int i = 0; i < 4; ++i) {
            unsigned o = (unsigned)(i * 4096 + w * 1024 + lane * 16);
            unsigned srcoff = o ^ (((o >> 9) & 7u) << 4);
            async16(gb + srcoff, (char*)&Bls[0][0] + (i * 4096 + w * 1024));
        }
    }

    // fused edge scatter (grid-stride over E); overlaps A-load / tile-0 DMA
    if (SCATTER) {
        int nthr = gridDim.x * 256;
        for (int e = blockIdx.x * 256 + tid; e < E; e += nthr) {
            int pos = atomicAdd(&cursor[edst[e]], 1);
            perm_src[pos] = esrc[e];
        }
    }

    // load A strip into registers (32 rows/wave, fused f32->bf16)
    bf16x8 a[2][8];
    #pragma unroll
    for (int m = 0; m < 2; ++m) {
        int row = row0 + rg * 32 + m * 16 + lrow;
        row = min(row, M - 1);
        if (AF32) {
            const float* ap = (const float*)Ain + (size_t)row * DIMV + lkg * 8;
            #pragma unroll
            for (int k0 = 0; k0 < 8; ++k0) {
                float4 f0 = *(const float4*)(ap + k0 * 32);
                float4 f1 = *(const float4*)(ap + k0 * 32 + 4);
                bf16x8 r;
                r[0] = (short)f2bf(f0.x); r[1] = (short)f2bf(f0.y);
                r[2] = (short)f2bf(f0.z); r[3] = (short)f2bf(f0.w);
                r[4] = (short)f2bf(f1.x); r[5] = (short)f2bf(f1.y);
                r[6] = (short)f2bf(f1.z); r[7] = (short)f2bf(f1.w);
                a[m][k0] = r;
            }
        } else {
            const unsigned short* ap = (const unsigned short*)Ain + (size_t)row * DIMV + lkg * 8;
            #pragma unroll
            for (int k0 = 0; k0 < 8; ++k0)
                a[m][k0] = *(const bf16x8*)(ap + k0 * 32);
        }
    }

    // drain everything once (incl. tile-0 DMA), then enter the counted loop
    asm volatile("s_waitcnt vmcnt(0)" ::: "memory");
    __builtin_amdgcn_s_barrier();

    const int c = cg * 16 + lrow;
    for (int t = 0; t < ntiles; ++t) {
        // prefetch tile t+1 into the other buffer; keep it in flight (vmcnt(4))
        if (t + 1 < ntiles) {
            const char* gb = (const char*)Wcat + (size_t)(t + 1) * 16384;
            #pragma unroll
            for (int i = 0; i < 4; ++i) {
                unsigned o = (unsigned)(i * 4096 + w * 1024 + lane * 16);
                unsigned srcoff = o ^ (((o >> 9) & 7u) << 4);
                async16(gb + srcoff, (char*)&Bls[(t + 1) & 1][0] + (i * 4096 + w * 1024));
            }
            asm volatile("s_waitcnt vmcnt(4)" ::: "memory");   // tile t's DMA done
        } else {
            asm volatile("s_waitcnt vmcnt(0)" ::: "memory");
        }
        __builtin_amdgcn_s_barrier();   // all waves' tile-t data in LDS

        const char* bls = (const char*)&Bls[t & 1][0];
        f32x4 acc0 = {0.f, 0.f, 0.f, 0.f};
        f32x4 acc1 = {0.f, 0.f, 0.f, 0.f};
        #pragma unroll
        for (int k0 = 0; k0 < 8; ++k0) {
            unsigned lin = (unsigned)c * 512 + (unsigned)k0 * 64 + (unsigned)lkg * 16;
            unsigned addr = lin ^ (((unsigned)c & 7u) << 4);
            bf16x8 bf = *(const bf16x8*)(bls + addr);
            acc0 = __builtin_amdgcn_mfma_f32_16x16x32_bf16(a[0][k0], bf, acc0, 0, 0, 0);
            acc1 = __builtin_amdgcn_mfma_f32_16x16x32_bf16(a[1][k0], bf, acc1, 0, 0, 0);
        }

        int mat = t >> 3;
        const float* bp = (mat == 0) ? b0 : (mat == 1 ? b1 : b2);
        int gcol = ((t & 7) << 5) + c;
        float bias = bp[gcol];
        unsigned cbase = (unsigned)mat * MATSTRIDE + gcol;
        #pragma unroll
        for (int m = 0; m < 2; ++m) {
            f32x4 av = m ? acc1 : acc0;
            #pragma unroll
            for (int r = 0; r < 4; ++r) {
                int row = row0 + rg * 32 + m * 16 + lkg * 4 + r;
                if (row < M) {
                    float val = av[r] + bias;
                    if (OF32)
                        ((float*)Cout)[(size_t)row * OSTRIDE + cbase] = val;
                    else
                        ((unsigned short*)Cout)[(size_t)row * OSTRIDE + cbase] = f2bf(val);
                }
            }
        }
        __builtin_amdgcn_s_barrier();   // reads of buf[t&1] retired before overwrite
    }
}

// ---------------- per-node edge-softmax attention ----------------
// one wave per dst node; 64 lanes = 8 heads x 8 lanes; lane owns 4 d-elems.
// Interleaved QKV rows: per edge ONE 32-bit base offset (src*768+col), q at +0,
// v at +512 (immediate). 2-deep register pipeline, 2 online-softmax states.

__global__ __launch_bounds__(256)
void node_attn(const unsigned short* __restrict__ QKV,
               const int* __restrict__ offsets, const int* __restrict__ perm_src,
               unsigned short* __restrict__ attn, int N) {
    int wid = blockIdx.x * (blockDim.x >> 6) + (threadIdx.x >> 6);
    if (wid >= N) return;
    int lane = threadIdx.x & 63;
    unsigned col = (unsigned)((lane >> 3) * DV + (lane & 7) * 4);

    ushort4 kr = *(const ushort4*)(QKV + (size_t)wid * QKVS + 256 + col);
    float k0 = bf2f(kr.x) * SCORE_SCALE, k1 = bf2f(kr.y) * SCORE_SCALE;
    float k2 = bf2f(kr.z) * SCORE_SCALE, k3 = bf2f(kr.w) * SCORE_SCALE;

    float mA = -INFINITY, lA = 0.f, aA0 = 0.f, aA1 = 0.f, aA2 = 0.f, aA3 = 0.f;
    float mB = -INFINITY, lB = 0.f, aB0 = 0.f, aB1 = 0.f, aB2 = 0.f, aB3 = 0.f;

    auto upd = [&](ushort4 qr, ushort4 vr, float& m, float& l,
                   float& a0, float& a1, float& a2, float& a3) {
        float d = bf2f(qr.x) * k0 + bf2f(qr.y) * k1 + bf2f(qr.z) * k2 + bf2f(qr.w) * k3;
        d += __shfl_xor(d, 1); d += __shfl_xor(d, 2); d += __shfl_xor(d, 4);
        float mn = fmaxf(m, d);
        float sc = EXPS(m - mn);
        float pe = EXPS(d - mn);
        l = l * sc + pe;
        a0 = a0 * sc + pe * bf2f(vr.x);
        a1 = a1 * sc + pe * bf2f(vr.y);
        a2 = a2 * sc + pe * bf2f(vr.z);
        a3 = a3 * sc + pe * bf2f(vr.w);
        m = mn;
    };

    int e0 = offsets[wid], e1 = offsets[wid + 1];
    int rem = e1 - e0;
    int S = rem >> 1;          // full pairs
    int p = e0;

    if (S >= 1) {
        unsigned o0 = (unsigned)perm_src[p] * QKVS + col;
        unsigned o1 = (unsigned)perm_src[p + 1] * QKVS + col;
        ushort4 qA0 = *(const ushort4*)(QKV + o0);
        ushort4 vA0 = *(const ushort4*)(QKV + o0 + 512);
        ushort4 qA1 = *(const ushort4*)(QKV + o1);
        ushort4 vA1 = *(const ushort4*)(QKV + o1 + 512);
        unsigned n0 = 0, n1 = 0;
        if (S >= 2) {
            n0 = (unsigned)perm_src[p + 2] * QKVS + col;
            n1 = (unsigned)perm_src[p + 3] * QKVS + col;
        }
        ushort4 qB0, qB1, vB0, vB1;

        int s = 0;
        while (s + 2 <= S) {
            qB0 = *(const ushort4*)(QKV + n0);
            vB0 = *(const ushort4*)(QKV + n0 + 512);
            qB1 = *(const ushort4*)(QKV + n1);
            vB1 = *(const ushort4*)(QKV + n1 + 512);
            if (s + 2 < S) {
                n0 = (unsigned)perm_src[p + 2 * s + 4] * QKVS + col;
                n1 = (unsigned)perm_src[p + 2 * s + 5] * QKVS + col;
            }
            upd(qA0, vA0, mA, lA, aA0, aA1, aA2, aA3);
            upd(qA1, vA1, mB, lB, aB0, aB1, aB2, aB3);

            if (s + 2 < S) {
                qA0 = *(const ushort4*)(QKV + n0);
                vA0 = *(const ushort4*)(QKV + n0 + 512);
                qA1 = *(const ushort4*)(QKV + n1);
                vA1 = *(const ushort4*)(QKV + n1 + 512);
                if (s + 3 < S) {
                    n0 = (unsigned)perm_src[p + 2 * s + 6] * QKVS + col;
                    n1 = (unsigned)perm_src[p + 2 * s + 7] * QKVS + col;
                }
            }
            upd(qB0, vB0, mA, lA, aA0, aA1, aA2, aA3);
            upd(qB1, vB1, mB, lB, aB0, aB1, aB2, aB3);
            s += 2;
        }
        if (s < S) {
            upd(qA0, vA0, mA, lA, aA0, aA1, aA2, aA3);
            upd(qA1, vA1, mB, lB, aB0, aB1, aB2, aB3);
        }
    }
    if (rem & 1) {
        unsigned o0 = (unsigned)perm_src[e1 - 1] * QKVS + col;
        ushort4 q0 = *(const ushort4*)(QKV + o0);
        ushort4 v0 = *(const ushort4*)(QKV + o0 + 512);
        upd(q0, v0, mA, lA, aA0, aA1, aA2, aA3);
    }

    // merge the two states
    float mn = fmaxf(mA, mB);
    float scA = (lA > 0.f) ? EXPS(mA - mn) : 0.f;
    float scB = (lB > 0.f) ? EXPS(mB - mn) : 0.f;
    float l = lA * scA + lB * scB;
    float o0 = aA0 * scA + aB0 * scB;
    float o1 = aA1 * scA + aB1 * scB;
    float o2 = aA2 * scA + aB2 * scB;
    float o3 = aA3 * scA + aB3 * scB;
    float inv = (l > 0.f) ? 1.f / l : 0.f;

    ushort4 o;
    o.x = f2bf(o0 * inv); o.y = f2bf(o1 * inv); o.z = f2bf(o2 * inv); o.w = f2bf(o3 * inv);
    *(ushort4*)(attn + (size_t)wid * DIMV + col) = o;
}

// ---------------- launcher ----------------

extern "C" void kernel_launch(void* const* d_in, const int* in_sizes, int n_in,
                              void* d_out, int out_size, void* d_ws, size_t ws_size,
                              hipStream_t stream) {
    const float* x  = (const float*)d_in[0];
    const float* Wq = (const float*)d_in[1];
    const float* bq = (const float*)d_in[2];
    const float* Wk = (const float*)d_in[3];
    const float* bk = (const float*)d_in[4];
    const float* Wv = (const float*)d_in[5];
    const float* bv = (const float*)d_in[6];
    const float* Wo = (const float*)d_in[7];
    const float* bo = (const float*)d_in[8];
    const int* src  = (const int*)d_in[9];
    const int* dst  = (const int*)d_in[10];
    int N = in_sizes[0] / DIMV;
    int E = in_sizes[9];
    float* out = (float*)d_out;

    char* p = (char*)d_ws;
    auto alloc = [&](size_t bytes) {
        char* r = p;
        p += (bytes + 255) & ~(size_t)255;
        return r;
    };
    unsigned short* Wcat = (unsigned short*)alloc((size_t)4 * 65536 * 2);   // [Wq|Wk|Wv|Wo] bf16
    unsigned short* QKV  = (unsigned short*)alloc((size_t)N * QKVS * 2);    // interleaved q|k|v
    unsigned short* attn = (unsigned short*)alloc((size_t)N * DIMV * 2);
    int* deg             = (int*)alloc((size_t)N * 4);
    int* offsets         = (int*)alloc((size_t)(N + 1) * 4);
    int* cursor          = (int*)alloc((size_t)N * 4);
    int* perm_src        = (int*)alloc((size_t)E * 4);
    int* bsum            = (int*)alloc((size_t)1024 * 4);

    // zero degrees, then weight conversion + fused degree count
    int nb = (N + 255) / 256;
    zero_i32<<<nb, 256, 0, stream>>>(deg, N);
    dim3 gw(64, 4);
    cvt_w_count<<<gw, 256, 0, stream>>>(Wq, Wk, Wv, Wo, Wcat, dst, deg, E);

    // scan: deg -> offsets/cursor
    block_sum<<<nb, 256, 0, stream>>>(deg, bsum, N);
    scan_bsum<<<1, 64, 0, stream>>>(bsum, nb);
    scan_final<<<nb, 256, 0, stream>>>(deg, bsum, offsets, cursor, N);

    // fused QKV projection (+ edge scatter prologue): x(f32) -> interleaved QKV(bf16)
    int gblocks = (N + 63) / 64;
    gemm_fused<true, false, QKVS, 256, true><<<gblocks, 256, 0, stream>>>(
        x, Wcat, bq, bk, bv, QKV, N, 24, src, dst, cursor, perm_src, E);

    node_attn<<<(N + 3) / 4, 256, 0, stream>>>(QKV, offsets, perm_src, attn, N);

    // output projection: attn(bf16) -> out(f32), 8 tiles (Wo = mat 3 of Wcat)
    gemm_fused<false, true, DIMV, 0, false><<<gblocks, 256, 0, stream>>>(
        attn, Wcat + (size_t)3 * 65536, bo, bo, bo, out, N, 8,
        nullptr, nullptr, nullptr, nullptr, 0);
}

// Round 7
// 284.366 us; speedup vs baseline: 1.1842x; 1.1842x over previous
//
#include <hip/hip_runtime.h>
#include <hip/hip_bf16.h>
#include <math.h>

#define DIMV 256
#define DV 32
#define QKVS 768   // interleaved row stride: q[256] | k[256] | v[256]

typedef __attribute__((ext_vector_type(8))) short bf16x8;
typedef __attribute__((ext_vector_type(4))) float f32x4;

#define EXPS(x) __expf(x)
#define SCORE_SCALE 0.17677669529663687f

static __device__ __forceinline__ unsigned short f2bf(float f) {
    unsigned x = __float_as_uint(f);
    x += 0x7FFF + ((x >> 16) & 1);   // round-to-nearest-even
    return (unsigned short)(x >> 16);
}
static __device__ __forceinline__ float bf2f(unsigned short u) {
    return __uint_as_float(((unsigned)u) << 16);
}

static __device__ __forceinline__ void async16(const void* g, void* lds) {
    __builtin_amdgcn_global_load_lds(
        (const __attribute__((address_space(1))) void*)g,
        (__attribute__((address_space(3))) void*)lds, 16, 0, 0);
}

// ---------------- weight f32 -> bf16 + fused degree count ----------------

__global__ void cvt_w_count(const float* __restrict__ Wq, const float* __restrict__ Wk,
                            const float* __restrict__ Wv, const float* __restrict__ Wo,
                            unsigned short* __restrict__ Wcat,
                            const int* __restrict__ dst, int* __restrict__ deg, int E) {
    const float* W = blockIdx.y == 0 ? Wq : blockIdx.y == 1 ? Wk : blockIdx.y == 2 ? Wv : Wo;
    int i = blockIdx.x * 256 + threadIdx.x;          // float4 index, 16384 per matrix
    float4 v = ((const float4*)W)[i];
    ushort4 o;
    o.x = f2bf(v.x); o.y = f2bf(v.y); o.z = f2bf(v.z); o.w = f2bf(v.w);
    ((ushort4*)(Wcat + (size_t)blockIdx.y * 65536))[i] = o;

    // fused degree count (grid-stride over E)
    int gid = (blockIdx.y * gridDim.x + blockIdx.x) * 256 + threadIdx.x;
    int nthr = gridDim.x * gridDim.y * 256;
    for (int e = gid; e < E; e += nthr) atomicAdd(&deg[dst[e]], 1);
}

// ---------------- CSR scan (R3 config — measured fast) ----------------

__global__ void zero_i32(int* __restrict__ p, int n) {
    int i = blockIdx.x * blockDim.x + threadIdx.x;
    if (i < n) p[i] = 0;
}

__global__ void block_sum(const int* __restrict__ deg, int* __restrict__ bsum, int n) {
    __shared__ int sm[256];
    int i = blockIdx.x * 256 + threadIdx.x;
    sm[threadIdx.x] = (i < n) ? deg[i] : 0;
    __syncthreads();
    for (int s = 128; s > 0; s >>= 1) {
        if (threadIdx.x < s) sm[threadIdx.x] += sm[threadIdx.x + s];
        __syncthreads();
    }
    if (threadIdx.x == 0) bsum[blockIdx.x] = sm[0];
}

__global__ void scan_bsum(int* __restrict__ bsum, int nb) {
    if (threadIdx.x == 0) {
        int r = 0;
        for (int i = 0; i < nb; ++i) { int v = bsum[i]; bsum[i] = r; r += v; }
    }
}

__global__ void scan_final(const int* __restrict__ deg, const int* __restrict__ bsum,
                           int* __restrict__ offsets, int* __restrict__ cursor, int n) {
    __shared__ int sm[256];
    int i = blockIdx.x * 256 + threadIdx.x;
    int v = (i < n) ? deg[i] : 0;
    sm[threadIdx.x] = v;
    __syncthreads();
    for (int s = 1; s < 256; s <<= 1) {
        int t = (threadIdx.x >= s) ? sm[threadIdx.x - s] : 0;
        __syncthreads();
        sm[threadIdx.x] += t;
        __syncthreads();
    }
    int excl = sm[threadIdx.x] - v + bsum[blockIdx.x];
    if (i < n) { offsets[i] = excl; cursor[i] = excl; }
    if (i == n - 1) offsets[n] = excl + v;
}

// ---------------- fused MFMA GEMM: C[mat] = A @ W[mat]^T + b[mat] ----------------
// A [M,256] (f32 or bf16) row-major; Wcat [nmat][256][256] bf16 row-major.
// A-strip in registers (read once). W tiles (32 cols x 256 K = 16 KB) double-
// buffered in LDS in FRAGMENT-MAJOR order: 16B frag (k0,lkg,c) at idx
// k0*128 + lkg*32 + c  -> ds_read_b128 is bank-uniform (2 lanes/bank, free).
// Staging uses per-lane inverse-mapped global source offsets (precomputed).
// K-loop: single s_barrier + counted vmcnt(8) per tile. Per-wave VMEM queue at
// the top of tile t is [DMA(t) x4 (older), stores(t-1) x8 (newer)]; in-order
// retirement means vmcnt(8) waits exactly for DMA(t), never for the stores.
// Biases live in LDS so no stray VMEM loads corrupt the queue count.
// Tail block (rows >= M-63) uses a fully-drained __syncthreads variant.

template<bool OF32, bool GUARD, int OSTRIDE, int MATSTRIDE>
static __device__ __forceinline__
void kloop(const bf16x8 (&a)[2][8], unsigned short (*Bls)[8192],
           const float* __restrict__ BiasLds, const unsigned short* __restrict__ Wcat,
           const unsigned* voff, void* __restrict__ Cout,
           int M, int ntiles, int row0, int rg, int cg, int lrow, int lkg, int w) {
    const int c = cg * 16 + lrow;
    for (int t = 0; t < ntiles; ++t) {
        if (GUARD) {
            __syncthreads();
        } else {
            asm volatile("s_waitcnt vmcnt(8)" ::: "memory");
            __builtin_amdgcn_s_barrier();
        }
        if (t + 1 < ntiles) {
            const char* gb = (const char*)Wcat + (size_t)(t + 1) * 16384;
            #pragma unroll
            for (int i = 0; i < 4; ++i)
                async16(gb + voff[i], (char*)&Bls[(t + 1) & 1][0] + (i * 4096 + w * 1024));
        }
        asm volatile("" ::: "memory");   // pin DMA issue before compute/stores

        const unsigned short* bls = &Bls[t & 1][0];
        f32x4 acc0 = {0.f, 0.f, 0.f, 0.f};
        f32x4 acc1 = {0.f, 0.f, 0.f, 0.f};
        #pragma unroll
        for (int k0 = 0; k0 < 8; ++k0) {
            const bf16x8 bf = *(const bf16x8*)(bls + (size_t)(k0 * 128 + lkg * 32 + c) * 8);
            acc0 = __builtin_amdgcn_mfma_f32_16x16x32_bf16(a[0][k0], bf, acc0, 0, 0, 0);
            acc1 = __builtin_amdgcn_mfma_f32_16x16x32_bf16(a[1][k0], bf, acc1, 0, 0, 0);
        }

        int mat = t >> 3;
        int gcol = ((t & 7) << 5) + c;
        float bias = BiasLds[mat * 256 + gcol];
        unsigned cbase = (unsigned)mat * MATSTRIDE + gcol;
        #pragma unroll
        for (int mf = 0; mf < 2; ++mf) {
            f32x4 av = mf ? acc1 : acc0;
            #pragma unroll
            for (int r = 0; r < 4; ++r) {
                int row = row0 + rg * 32 + mf * 16 + lkg * 4 + r;
                if (!GUARD || row < M) {
                    float val = av[r] + bias;
                    if (OF32)
                        ((float*)Cout)[(size_t)row * OSTRIDE + cbase] = val;
                    else
                        ((unsigned short*)Cout)[(size_t)row * OSTRIDE + cbase] = f2bf(val);
                }
            }
        }
    }
}

template<bool AF32, bool OF32, int OSTRIDE, int MATSTRIDE, bool SCATTER>
__global__ __launch_bounds__(256, 4)
void gemm_fused(const void* __restrict__ Ain,
                const unsigned short* __restrict__ Wcat,
                const float* __restrict__ b0, const float* __restrict__ b1,
                const float* __restrict__ b2,
                void* __restrict__ Cout, int M, int ntiles, int scb,
                const int* __restrict__ esrc, const int* __restrict__ edst,
                int* __restrict__ cursor, int* __restrict__ perm_src, int E) {
    __shared__ unsigned short Bls[2][8192];   // 2 x 16 KB, fragment-major
    __shared__ float BiasLds[768];

    // leading blocks: edge scatter (overlaps with gemm blocks), no barriers
    if (SCATTER && (int)blockIdx.x < scb) {
        int nthr = scb * 256;
        for (int e = (int)blockIdx.x * 256 + (int)threadIdx.x; e < E; e += nthr)
            perm_src[atomicAdd(&cursor[edst[e]], 1)] = esrc[e];
        return;
    }
    const int bid = (int)blockIdx.x - (SCATTER ? scb : 0);
    const int tid = threadIdx.x;
    const int w = tid >> 6, lane = tid & 63;
    const int rg = w >> 1, cg = w & 1;
    const int lrow = lane & 15, lkg = lane >> 4;
    const int row0 = bid * 64;

    // biases -> LDS (keeps VMEM queue clean in the K-loop)
    int nmat = ntiles >> 3;
    for (int i = tid; i < nmat * 256; i += 256) {
        const float* bp = (i >> 8) == 0 ? b0 : ((i >> 8) == 1 ? b1 : b2);
        BiasLds[i] = bp[i & 255];
    }

    // per-lane staging source offsets: inverse of fragment-major LDS order
    unsigned voff[4];
    #pragma unroll
    for (int i = 0; i < 4; ++i) {
        unsigned idx = (unsigned)(i * 256 + w * 64 + lane);    // 16B-frag index
        voff[i] = (idx & 31u) * 512u + (idx >> 7) * 64u + ((idx >> 5) & 3u) * 16u;
    }
    // stage tile 0
    #pragma unroll
    for (int i = 0; i < 4; ++i)
        async16((const char*)Wcat + voff[i], (char*)&Bls[0][0] + (i * 4096 + w * 1024));

    // load A strip into registers (32 rows/wave, fused f32->bf16)
    bf16x8 a[2][8];
    #pragma unroll
    for (int m = 0; m < 2; ++m) {
        int row = row0 + rg * 32 + m * 16 + lrow;
        row = min(row, M - 1);
        if (AF32) {
            const float* ap = (const float*)Ain + (size_t)row * DIMV + lkg * 8;
            #pragma unroll
            for (int k0 = 0; k0 < 8; ++k0) {
                float4 f0 = *(const float4*)(ap + k0 * 32);
                float4 f1 = *(const float4*)(ap + k0 * 32 + 4);
                bf16x8 r;
                r[0] = (short)f2bf(f0.x); r[1] = (short)f2bf(f0.y);
                r[2] = (short)f2bf(f0.z); r[3] = (short)f2bf(f0.w);
                r[4] = (short)f2bf(f1.x); r[5] = (short)f2bf(f1.y);
                r[6] = (short)f2bf(f1.z); r[7] = (short)f2bf(f1.w);
                a[m][k0] = r;
            }
        } else {
            const unsigned short* ap = (const unsigned short*)Ain + (size_t)row * DIMV + lkg * 8;
            #pragma unroll
            for (int k0 = 0; k0 < 8; ++k0)
                a[m][k0] = *(const bf16x8*)(ap + k0 * 32);
        }
    }

    // drain prologue (tile-0 DMA, A loads, bias LDS writes), then K-loop
    asm volatile("s_waitcnt vmcnt(0) lgkmcnt(0)" ::: "memory");
    __builtin_amdgcn_s_barrier();

    if (row0 + 64 <= M)
        kloop<OF32, false, OSTRIDE, MATSTRIDE>(a, Bls, BiasLds, Wcat, voff, Cout,
                                               M, ntiles, row0, rg, cg, lrow, lkg, w);
    else
        kloop<OF32, true, OSTRIDE, MATSTRIDE>(a, Bls, BiasLds, Wcat, voff, Cout,
                                              M, ntiles, row0, rg, cg, lrow, lkg, w);
}

// ---------------- per-node edge-softmax attention (unchanged, measured 114 µs) ----

__global__ __launch_bounds__(256)
void node_attn(const unsigned short* __restrict__ QKV,
               const int* __restrict__ offsets, const int* __restrict__ perm_src,
               unsigned short* __restrict__ attn, int N) {
    int wid = blockIdx.x * (blockDim.x >> 6) + (threadIdx.x >> 6);
    if (wid >= N) return;
    int lane = threadIdx.x & 63;
    unsigned col = (unsigned)((lane >> 3) * DV + (lane & 7) * 4);

    ushort4 kr = *(const ushort4*)(QKV + (size_t)wid * QKVS + 256 + col);
    float k0 = bf2f(kr.x) * SCORE_SCALE, k1 = bf2f(kr.y) * SCORE_SCALE;
    float k2 = bf2f(kr.z) * SCORE_SCALE, k3 = bf2f(kr.w) * SCORE_SCALE;

    float mA = -INFINITY, lA = 0.f, aA0 = 0.f, aA1 = 0.f, aA2 = 0.f, aA3 = 0.f;
    float mB = -INFINITY, lB = 0.f, aB0 = 0.f, aB1 = 0.f, aB2 = 0.f, aB3 = 0.f;

    auto upd = [&](ushort4 qr, ushort4 vr, float& m, float& l,
                   float& a0, float& a1, float& a2, float& a3) {
        float d = bf2f(qr.x) * k0 + bf2f(qr.y) * k1 + bf2f(qr.z) * k2 + bf2f(qr.w) * k3;
        d += __shfl_xor(d, 1); d += __shfl_xor(d, 2); d += __shfl_xor(d, 4);
        float mn = fmaxf(m, d);
        float sc = EXPS(m - mn);
        float pe = EXPS(d - mn);
        l = l * sc + pe;
        a0 = a0 * sc + pe * bf2f(vr.x);
        a1 = a1 * sc + pe * bf2f(vr.y);
        a2 = a2 * sc + pe * bf2f(vr.z);
        a3 = a3 * sc + pe * bf2f(vr.w);
        m = mn;
    };

    int e0 = offsets[wid], e1 = offsets[wid + 1];
    int rem = e1 - e0;
    int S = rem >> 1;          // full pairs
    int p = e0;

    if (S >= 1) {
        unsigned o0 = (unsigned)perm_src[p] * QKVS + col;
        unsigned o1 = (unsigned)perm_src[p + 1] * QKVS + col;
        ushort4 qA0 = *(const ushort4*)(QKV + o0);
        ushort4 vA0 = *(const ushort4*)(QKV + o0 + 512);
        ushort4 qA1 = *(const ushort4*)(QKV + o1);
        ushort4 vA1 = *(const ushort4*)(QKV + o1 + 512);
        unsigned n0 = 0, n1 = 0;
        if (S >= 2) {
            n0 = (unsigned)perm_src[p + 2] * QKVS + col;
            n1 = (unsigned)perm_src[p + 3] * QKVS + col;
        }
        ushort4 qB0, qB1, vB0, vB1;

        int s = 0;
        while (s + 2 <= S) {
            qB0 = *(const ushort4*)(QKV + n0);
            vB0 = *(const ushort4*)(QKV + n0 + 512);
            qB1 = *(const ushort4*)(QKV + n1);
            vB1 = *(const ushort4*)(QKV + n1 + 512);
            if (s + 2 < S) {
                n0 = (unsigned)perm_src[p + 2 * s + 4] * QKVS + col;
                n1 = (unsigned)perm_src[p + 2 * s + 5] * QKVS + col;
            }
            upd(qA0, vA0, mA, lA, aA0, aA1, aA2, aA3);
            upd(qA1, vA1, mB, lB, aB0, aB1, aB2, aB3);

            if (s + 2 < S) {
                qA0 = *(const ushort4*)(QKV + n0);
                vA0 = *(const ushort4*)(QKV + n0 + 512);
                qA1 = *(const ushort4*)(QKV + n1);
                vA1 = *(const ushort4*)(QKV + n1 + 512);
                if (s + 3 < S) {
                    n0 = (unsigned)perm_src[p + 2 * s + 6] * QKVS + col;
                    n1 = (unsigned)perm_src[p + 2 * s + 7] * QKVS + col;
                }
            }
            upd(qB0, vB0, mA, lA, aA0, aA1, aA2, aA3);
            upd(qB1, vB1, mB, lB, aB0, aB1, aB2, aB3);
            s += 2;
        }
        if (s < S) {
            upd(qA0, vA0, mA, lA, aA0, aA1, aA2, aA3);
            upd(qA1, vA1, mB, lB, aB0, aB1, aB2, aB3);
        }
    }
    if (rem & 1) {
        unsigned o0 = (unsigned)perm_src[e1 - 1] * QKVS + col;
        ushort4 q0 = *(const ushort4*)(QKV + o0);
        ushort4 v0 = *(const ushort4*)(QKV + o0 + 512);
        upd(q0, v0, mA, lA, aA0, aA1, aA2, aA3);
    }

    // merge the two states
    float mn = fmaxf(mA, mB);
    float scA = (lA > 0.f) ? EXPS(mA - mn) : 0.f;
    float scB = (lB > 0.f) ? EXPS(mB - mn) : 0.f;
    float l = lA * scA + lB * scB;
    float o0 = aA0 * scA + aB0 * scB;
    float o1 = aA1 * scA + aB1 * scB;
    float o2 = aA2 * scA + aB2 * scB;
    float o3 = aA3 * scA + aB3 * scB;
    float inv = (l > 0.f) ? 1.f / l : 0.f;

    ushort4 o;
    o.x = f2bf(o0 * inv); o.y = f2bf(o1 * inv); o.z = f2bf(o2 * inv); o.w = f2bf(o3 * inv);
    *(ushort4*)(attn + (size_t)wid * DIMV + col) = o;
}

// ---------------- launcher ----------------

extern "C" void kernel_launch(void* const* d_in, const int* in_sizes, int n_in,
                              void* d_out, int out_size, void* d_ws, size_t ws_size,
                              hipStream_t stream) {
    const float* x  = (const float*)d_in[0];
    const float* Wq = (const float*)d_in[1];
    const float* bq = (const float*)d_in[2];
    const float* Wk = (const float*)d_in[3];
    const float* bk = (const float*)d_in[4];
    const float* Wv = (const float*)d_in[5];
    const float* bv = (const float*)d_in[6];
    const float* Wo = (const float*)d_in[7];
    const float* bo = (const float*)d_in[8];
    const int* src  = (const int*)d_in[9];
    const int* dst  = (const int*)d_in[10];
    int N = in_sizes[0] / DIMV;
    int E = in_sizes[9];
    float* out = (float*)d_out;

    char* p = (char*)d_ws;
    auto alloc = [&](size_t bytes) {
        char* r = p;
        p += (bytes + 255) & ~(size_t)255;
        return r;
    };
    unsigned short* Wcat = (unsigned short*)alloc((size_t)4 * 65536 * 2);   // [Wq|Wk|Wv|Wo] bf16
    unsigned short* QKV  = (unsigned short*)alloc((size_t)N * QKVS * 2);    // interleaved q|k|v
    unsigned short* attn = (unsigned short*)alloc((size_t)N * DIMV * 2);
    int* deg             = (int*)alloc((size_t)N * 4);
    int* offsets         = (int*)alloc((size_t)(N + 1) * 4);
    int* cursor          = (int*)alloc((size_t)N * 4);
    int* perm_src        = (int*)alloc((size_t)E * 4);
    int* bsum            = (int*)alloc((size_t)1024 * 4);

    // zero degrees, then weight conversion + fused degree count
    int nb = (N + 255) / 256;
    zero_i32<<<nb, 256, 0, stream>>>(deg, N);
    dim3 gw(64, 4);
    cvt_w_count<<<gw, 256, 0, stream>>>(Wq, Wk, Wv, Wo, Wcat, dst, deg, E);

    // scan: deg -> offsets/cursor
    block_sum<<<nb, 256, 0, stream>>>(deg, bsum, N);
    scan_bsum<<<1, 64, 0, stream>>>(bsum, nb);
    scan_final<<<nb, 256, 0, stream>>>(deg, bsum, offsets, cursor, N);

    // fused QKV projection; leading 160 blocks do the edge scatter concurrently
    int gemmBlocks = (N + 63) / 64;
    const int SCB = 160;
    gemm_fused<true, false, QKVS, 256, true><<<SCB + gemmBlocks, 256, 0, stream>>>(
        x, Wcat, bq, bk, bv, QKV, N, 24, SCB, src, dst, cursor, perm_src, E);

    node_attn<<<(N + 3) / 4, 256, 0, stream>>>(QKV, offsets, perm_src, attn, N);

    // output projection: attn(bf16) -> out(f32), 8 tiles (Wo = mat 3 of Wcat)
    gemm_fused<false, true, DIMV, 0, false><<<gemmBlocks, 256, 0, stream>>>(
        attn, Wcat + (size_t)3 * 65536, bo, bo, bo, out, N, 8,
        0, nullptr, nullptr, nullptr, nullptr, 0);
}